// Round 1
// baseline (401.787 us; speedup 1.0000x reference)
//
#include <hip/hip_runtime.h>
#include <hip/hip_bf16.h>

#define N_NODES 50000
#define N_EDGES 800000
#define IN_DIM 128
#define OUT_DIM 64
#define NEG_SLOPE 0.01f

// Monotone float <-> uint mapping so atomicMax(unsigned) implements float max.
__device__ __forceinline__ unsigned fenc(float f) {
  unsigned b = __float_as_uint(f);
  return (b & 0x80000000u) ? ~b : (b | 0x80000000u);
}
__device__ __forceinline__ float fdec(unsigned u) {
  unsigned b = (u & 0x80000000u) ? (u & 0x7FFFFFFFu) : ~u;
  return __uint_as_float(b);
}

// Stage 1: z = features @ fc_w^T  (wave-per-node; lane j owns output j),
// plus a_src[n] = z[n].attn_w[:64], a_dst[n] = z[n].attn_w[64:].
__global__ __launch_bounds__(256, 2) void gat_z(
    const float* __restrict__ feat, const float* __restrict__ fcw,
    const float* __restrict__ attnw, float* __restrict__ z,
    float* __restrict__ asrc, float* __restrict__ adst) {
  const int lane = threadIdx.x & 63;
  const int wave = (blockIdx.x * blockDim.x + threadIdx.x) >> 6;
  const int nwaves = (gridDim.x * blockDim.x) >> 6;

  // lane j holds fc_w row j in VGPRs (128 floats)
  float w[IN_DIM];
  {
    const float4* wr = (const float4*)(fcw + lane * IN_DIM);
#pragma unroll
    for (int i = 0; i < IN_DIM / 4; ++i) ((float4*)w)[i] = wr[i];
  }
  const float aws = attnw[lane];
  const float awd = attnw[OUT_DIM + lane];

  for (int node = wave; node < N_NODES; node += nwaves) {
    // node is wave-uniform: force scalar (SGPR) loads of the feature row
    const int ns = __builtin_amdgcn_readfirstlane(node);
    const float* __restrict__ fr = feat + (size_t)ns * IN_DIM;
    float a0 = 0.f, a1 = 0.f, a2 = 0.f, a3 = 0.f;
#pragma unroll
    for (int k = 0; k < IN_DIM; k += 4) {
      a0 = fmaf(fr[k + 0], w[k + 0], a0);
      a1 = fmaf(fr[k + 1], w[k + 1], a1);
      a2 = fmaf(fr[k + 2], w[k + 2], a2);
      a3 = fmaf(fr[k + 3], w[k + 3], a3);
    }
    float acc = (a0 + a1) + (a2 + a3);
    z[(size_t)ns * OUT_DIM + lane] = acc;

    float s = acc * aws, d = acc * awd;
#pragma unroll
    for (int off = 32; off; off >>= 1) {
      s += __shfl_xor(s, off, 64);
      d += __shfl_xor(d, off, 64);
    }
    if (lane == 0) {
      asrc[ns] = s;
      adst[ns] = d;
    }
  }
}

// Stage 2: per-edge raw score e = leaky_relu(a_src[src] + a_dst[dst]),
// and segment max over dst via encoded atomicMax.
__global__ __launch_bounds__(256) void gat_edge(
    const float* __restrict__ asrc, const float* __restrict__ adst,
    const int* __restrict__ src, const int* __restrict__ dst,
    float* __restrict__ e, unsigned* __restrict__ emax) {
  int t = blockIdx.x * blockDim.x + threadIdx.x;
  if (t >= N_EDGES) return;
  float v = asrc[src[t]] + adst[dst[t]];
  v = v > 0.f ? v : NEG_SLOPE * v;
  e[t] = v;
  atomicMax(emax + dst[t], fenc(v));
}

// Stage 3: w = exp(e - emax[dst]); denom += w; num[dst] += w * z[src].
// One wave processes 64 edges: scalar phase lane-per-edge, then 64 broadcast
// iterations with a coalesced 256B z-row read + 64 consecutive atomicAdds.
__global__ __launch_bounds__(256) void gat_scatter(
    const float* __restrict__ z, const float* __restrict__ e,
    const unsigned* __restrict__ emax, const int* __restrict__ src,
    const int* __restrict__ dst, float* __restrict__ denom,
    float* __restrict__ num) {
  const int lane = threadIdx.x & 63;
  const int wave = (blockIdx.x * blockDim.x + threadIdx.x) >> 6;
  const int eid = wave * 64 + lane;  // N_EDGES == 12500*64, no tail
  int s = src[eid];
  int d = dst[eid];
  float w = __expf(e[eid] - fdec(emax[d]));
  atomicAdd(denom + d, w);
#pragma unroll 1
  for (int i = 0; i < 64; ++i) {
    int si = __shfl(s, i, 64);
    int di = __shfl(d, i, 64);
    float wi = __shfl(w, i, 64);
    atomicAdd(num + (size_t)di * OUT_DIM + lane, wi * z[(size_t)si * OUT_DIM + lane]);
  }
}

// Stage 4: h = elu(num / max(denom,>0 else 1)), in-place on d_out.
__global__ __launch_bounds__(256) void gat_final(
    float* __restrict__ out, const float* __restrict__ denom) {
  int t = blockIdx.x * blockDim.x + threadIdx.x;
  float dn = denom[t >> 6];
  dn = dn > 0.f ? dn : 1.f;
  float h = out[t] / dn;
  out[t] = h > 0.f ? h : expm1f(h);
}

extern "C" void kernel_launch(void* const* d_in, const int* in_sizes, int n_in,
                              void* d_out, int out_size, void* d_ws, size_t ws_size,
                              hipStream_t stream) {
  const float* feat  = (const float*)d_in[0];
  const float* fcw   = (const float*)d_in[1];
  const float* attnw = (const float*)d_in[2];
  const int* src     = (const int*)d_in[3];
  const int* dst     = (const int*)d_in[4];
  float* out = (float*)d_out;

  char* ws = (char*)d_ws;
  float* z = (float*)ws;          ws += (size_t)N_NODES * OUT_DIM * sizeof(float);  // 12.8 MB
  float* e = (float*)ws;          ws += (size_t)N_EDGES * sizeof(float);            // 3.2 MB
  float* asrc = (float*)ws;       ws += (size_t)N_NODES * sizeof(float);
  float* adst = (float*)ws;       ws += (size_t)N_NODES * sizeof(float);
  unsigned* emax = (unsigned*)ws; ws += (size_t)N_NODES * sizeof(unsigned);
  float* denom = (float*)ws;      ws += (size_t)N_NODES * sizeof(float);

  // num lives in d_out (in-place finalize). emax=0 encodes "-inf" sentinel
  // (any real float encodes > 0); denom=0 for empty-dst nodes.
  hipMemsetAsync(d_out, 0, (size_t)out_size * sizeof(float), stream);
  hipMemsetAsync(emax, 0, (size_t)N_NODES * sizeof(unsigned), stream);
  hipMemsetAsync(denom, 0, (size_t)N_NODES * sizeof(float), stream);

  gat_z<<<800, 256, 0, stream>>>(feat, fcw, attnw, z, asrc, adst);
  gat_edge<<<(N_EDGES + 255) / 256, 256, 0, stream>>>(asrc, adst, src, dst, e, emax);
  gat_scatter<<<N_EDGES / 64 / 4, 256, 0, stream>>>(z, e, emax, src, dst, denom, out);
  gat_final<<<(N_NODES * OUT_DIM) / 256, 256, 0, stream>>>(out, denom);
}

// Round 2
// 368.519 us; speedup vs baseline: 1.0903x; 1.0903x over previous
//
#include <hip/hip_runtime.h>
#include <hip/hip_bf16.h>

#define N_NODES 50000
#define N_EDGES 800000
#define IN_DIM 128
#define OUT_DIM 64
#define NEG_SLOPE 0.01f
#define NEG_INF (-3.0e38f)

// ---------------------------------------------------------------------------
// Stage 1: z = feat @ fcw^T (wave-per-node, lane j = output col j),
// plus a_src = z . attn_w[:64], a_dst = z . attn_w[64:].
// Feature row delivered via coalesced float2 vector load -> LDS broadcast
// (replaces R1's dependent s_load chain).
// ---------------------------------------------------------------------------
__global__ __launch_bounds__(256, 2) void gat_z(
    const float* __restrict__ feat, const float* __restrict__ fcw,
    const float* __restrict__ attnw, float* __restrict__ z,
    float* __restrict__ asrc, float* __restrict__ adst) {
  __shared__ float rows[4][IN_DIM];  // one row buffer per wave
  const int lane = threadIdx.x & 63;
  const int wslot = threadIdx.x >> 6;
  const int wave = (blockIdx.x * blockDim.x + threadIdx.x) >> 6;
  const int nwaves = (gridDim.x * blockDim.x) >> 6;

  // lane j holds fc_w row j (128 floats) in VGPRs
  float w[IN_DIM];
  {
    const float4* wr = (const float4*)(fcw + (size_t)lane * IN_DIM);
#pragma unroll
    for (int i = 0; i < IN_DIM / 4; ++i) ((float4*)w)[i] = wr[i];
  }
  const float aws = attnw[lane];
  const float awd = attnw[OUT_DIM + lane];

  int node = wave;
  float2 cur = make_float2(0.f, 0.f);
  if (node < N_NODES)
    cur = *(const float2*)(feat + (size_t)node * IN_DIM + 2 * lane);

  for (; node < N_NODES; node += nwaves) {
    ((float2*)rows[wslot])[lane] = cur;  // wave-private slot: no barrier needed
    // prefetch next row while we compute (independent of LDS ops)
    int nxt = node + nwaves;
    float2 nf = make_float2(0.f, 0.f);
    if (nxt < N_NODES)
      nf = *(const float2*)(feat + (size_t)nxt * IN_DIM + 2 * lane);

    float a0 = 0.f, a1 = 0.f, a2 = 0.f, a3 = 0.f;
#pragma unroll
    for (int k = 0; k < IN_DIM; k += 4) {
      const float4 f = *(const float4*)&rows[wslot][k];  // LDS broadcast
      a0 = fmaf(f.x, w[k + 0], a0);
      a1 = fmaf(f.y, w[k + 1], a1);
      a2 = fmaf(f.z, w[k + 2], a2);
      a3 = fmaf(f.w, w[k + 3], a3);
    }
    float acc = (a0 + a1) + (a2 + a3);
    z[(size_t)node * OUT_DIM + lane] = acc;

    float s = acc * aws, d = acc * awd;
#pragma unroll
    for (int off = 32; off; off >>= 1) {
      s += __shfl_xor(s, off, 64);
      d += __shfl_xor(d, off, 64);
    }
    if (lane == 0) {
      asrc[node] = s;
      adst[node] = d;
    }
    cur = nf;
  }
}

// ---------------------------------------------------------------------------
// CSR build: histogram of dst, exclusive scan, bucket-scatter of src ids.
// ---------------------------------------------------------------------------
__global__ __launch_bounds__(256) void gat_hist(const int* __restrict__ dst,
                                                int* __restrict__ counts) {
  int t = blockIdx.x * blockDim.x + threadIdx.x;
  if (t < N_EDGES) atomicAdd(counts + dst[t], 1);
}

// Single 1024-thread block: chunked serial sums + Hillis-Steele scan of 1024
// partials. Writes exclusive offsets[0..N] and initializes cursor=offsets.
__global__ __launch_bounds__(1024) void gat_scan(const int* __restrict__ counts,
                                                 int* __restrict__ offsets,
                                                 int* __restrict__ cursor) {
  __shared__ int part[1024];
  const int t = threadIdx.x;
  const int CH = (N_NODES + 1023) / 1024;  // 49
  const int b = t * CH;
  const int e = min(b + CH, N_NODES);
  int s = 0;
  for (int i = b; i < e; ++i) s += counts[i];
  part[t] = s;
  __syncthreads();
  for (int off = 1; off < 1024; off <<= 1) {
    int u = (t >= off) ? part[t - off] : 0;
    __syncthreads();
    part[t] += u;
    __syncthreads();
  }
  int run = part[t] - s;  // exclusive base of this chunk
  for (int i = b; i < e; ++i) {
    offsets[i] = run;
    cursor[i] = run;
    run += counts[i];
  }
  if (t == 1023) offsets[N_NODES] = part[1023];
}

__global__ __launch_bounds__(256) void gat_escatter(
    const int* __restrict__ src, const int* __restrict__ dst,
    int* __restrict__ cursor, int* __restrict__ ssorted) {
  int t = blockIdx.x * blockDim.x + threadIdx.x;
  if (t >= N_EDGES) return;
  int d = dst[t];
  int p = atomicAdd(cursor + d, 1);
  ssorted[p] = src[t];
}

// ---------------------------------------------------------------------------
// Aggregation: one wave per dst node. Gather incoming edges, online softmax
// via wave shuffles, accumulate w * z[src] in registers (lane = column),
// fused divide + ELU, one coalesced 256B store. No atomics.
// ---------------------------------------------------------------------------
__global__ __launch_bounds__(256) void gat_agg(
    const float* __restrict__ z, const float* __restrict__ asrc,
    const float* __restrict__ adst, const int* __restrict__ offsets,
    const int* __restrict__ ssorted, float* __restrict__ out) {
  const int lane = threadIdx.x & 63;
  const int node = (blockIdx.x * blockDim.x + threadIdx.x) >> 6;
  if (node >= N_NODES) return;
  const int o0 = offsets[node];
  const int o1 = offsets[node + 1];
  if (o0 == o1) {  // no incoming edges: num=0, denom->1, elu(0)=0
    out[(size_t)node * OUT_DIM + lane] = 0.f;
    return;
  }
  const float ad = adst[node];

  // pass 1: segment max of leaky_relu(asrc[src] + ad)
  float m = NEG_INF;
  for (int base = o0; base < o1; base += 64) {
    int idx = base + lane;
    float ev = NEG_INF;
    if (idx < o1) {
      float v = asrc[ssorted[idx]] + ad;
      ev = v > 0.f ? v : NEG_SLOPE * v;
    }
#pragma unroll
    for (int off = 32; off; off >>= 1) ev = fmaxf(ev, __shfl_xor(ev, off, 64));
    m = fmaxf(m, ev);
  }

  // pass 2: w = exp(e - m); denom; acc += w_j * z[src_j][lane]
  float acc = 0.f, dsum = 0.f;
  for (int base = o0; base < o1; base += 64) {
    int idx = base + lane;
    int s = 0;
    float w = 0.f;
    if (idx < o1) {
      s = ssorted[idx];
      float v = asrc[s] + ad;
      v = v > 0.f ? v : NEG_SLOPE * v;
      w = __expf(v - m);
    }
    dsum += w;
    const int cnt = min(64, o1 - base);
    for (int j = 0; j < cnt; ++j) {
      float wj = __shfl(w, j, 64);   // uniform j -> v_readlane
      int sj = __shfl(s, j, 64);
      acc = fmaf(wj, z[(size_t)sj * OUT_DIM + lane], acc);
    }
  }
#pragma unroll
  for (int off = 32; off; off >>= 1) dsum += __shfl_xor(dsum, off, 64);

  float h = acc / (dsum > 0.f ? dsum : 1.f);
  out[(size_t)node * OUT_DIM + lane] = h > 0.f ? h : expm1f(h);
}

// ---------------------------------------------------------------------------
extern "C" void kernel_launch(void* const* d_in, const int* in_sizes, int n_in,
                              void* d_out, int out_size, void* d_ws, size_t ws_size,
                              hipStream_t stream) {
  const float* feat  = (const float*)d_in[0];
  const float* fcw   = (const float*)d_in[1];
  const float* attnw = (const float*)d_in[2];
  const int* src     = (const int*)d_in[3];
  const int* dst     = (const int*)d_in[4];
  float* out = (float*)d_out;

  char* ws = (char*)d_ws;
  float* z = (float*)ws;      ws += (size_t)N_NODES * OUT_DIM * sizeof(float);  // 12.8 MB
  float* asrc = (float*)ws;   ws += (size_t)N_NODES * sizeof(float);
  float* adst = (float*)ws;   ws += (size_t)N_NODES * sizeof(float);
  int* counts = (int*)ws;     ws += (size_t)N_NODES * sizeof(int);
  int* cursor = (int*)ws;     ws += (size_t)N_NODES * sizeof(int);
  int* offsets = (int*)ws;    ws += (size_t)(N_NODES + 1) * sizeof(int);
  int* ssorted = (int*)ws;    ws += (size_t)N_EDGES * sizeof(int);              // 3.2 MB

  hipMemsetAsync(counts, 0, (size_t)N_NODES * sizeof(int), stream);

  gat_z<<<800, 256, 0, stream>>>(feat, fcw, attnw, z, asrc, adst);
  gat_hist<<<(N_EDGES + 255) / 256, 256, 0, stream>>>(dst, counts);
  gat_scan<<<1, 1024, 0, stream>>>(counts, offsets, cursor);
  gat_escatter<<<(N_EDGES + 255) / 256, 256, 0, stream>>>(src, dst, cursor, ssorted);
  gat_agg<<<(N_NODES * 64 + 255) / 256, 256, 0, stream>>>(z, asrc, adst, offsets, ssorted, out);
}

// Round 3
// 264.579 us; speedup vs baseline: 1.5186x; 1.3929x over previous
//
#include <hip/hip_runtime.h>
#include <hip/hip_bf16.h>

#define N_NODES 50000
#define N_EDGES 800000
#define IN_DIM 128
#define OUT_DIM 64
#define NEG_SLOPE 0.01f
#define NEG_INF (-3.0e38f)

#define N_I4 (N_NODES / 4)          // 12500 int4 elements (N_NODES % 4 == 0)
#define N_SBLK ((N_I4 + 255) / 256) // 49 scan blocks (1024 nodes each)

// ---------------------------------------------------------------------------
// Stage 1: z = feat @ fcw^T (wave-per-node, lane j = output col j),
// plus a_src = z . attn_w[:64], a_dst = z . attn_w[64:].
// ---------------------------------------------------------------------------
__global__ __launch_bounds__(256, 2) void gat_z(
    const float* __restrict__ feat, const float* __restrict__ fcw,
    const float* __restrict__ attnw, float* __restrict__ z,
    float* __restrict__ asrc, float* __restrict__ adst) {
  __shared__ float rows[4][IN_DIM];  // one row buffer per wave
  const int lane = threadIdx.x & 63;
  const int wslot = threadIdx.x >> 6;
  const int wave = (blockIdx.x * blockDim.x + threadIdx.x) >> 6;
  const int nwaves = (gridDim.x * blockDim.x) >> 6;

  float w[IN_DIM];
  {
    const float4* wr = (const float4*)(fcw + (size_t)lane * IN_DIM);
#pragma unroll
    for (int i = 0; i < IN_DIM / 4; ++i) ((float4*)w)[i] = wr[i];
  }
  const float aws = attnw[lane];
  const float awd = attnw[OUT_DIM + lane];

  int node = wave;
  float2 cur = make_float2(0.f, 0.f);
  if (node < N_NODES)
    cur = *(const float2*)(feat + (size_t)node * IN_DIM + 2 * lane);

  for (; node < N_NODES; node += nwaves) {
    ((float2*)rows[wslot])[lane] = cur;
    int nxt = node + nwaves;
    float2 nf = make_float2(0.f, 0.f);
    if (nxt < N_NODES)
      nf = *(const float2*)(feat + (size_t)nxt * IN_DIM + 2 * lane);

    float a0 = 0.f, a1 = 0.f, a2 = 0.f, a3 = 0.f;
#pragma unroll
    for (int k = 0; k < IN_DIM; k += 4) {
      const float4 f = *(const float4*)&rows[wslot][k];
      a0 = fmaf(f.x, w[k + 0], a0);
      a1 = fmaf(f.y, w[k + 1], a1);
      a2 = fmaf(f.z, w[k + 2], a2);
      a3 = fmaf(f.w, w[k + 3], a3);
    }
    float acc = (a0 + a1) + (a2 + a3);
    z[(size_t)node * OUT_DIM + lane] = acc;

    float s = acc * aws, d = acc * awd;
#pragma unroll
    for (int off = 32; off; off >>= 1) {
      s += __shfl_xor(s, off, 64);
      d += __shfl_xor(d, off, 64);
    }
    if (lane == 0) {
      asrc[node] = s;
      adst[node] = d;
    }
    cur = nf;
  }
}

// ---------------------------------------------------------------------------
// CSR build: histogram, 3-kernel hierarchical exclusive scan, bucket scatter.
// ---------------------------------------------------------------------------
__global__ __launch_bounds__(256) void gat_hist(const int* __restrict__ dst,
                                                int* __restrict__ counts) {
  int t = blockIdx.x * blockDim.x + threadIdx.x;
  if (t < N_EDGES) atomicAdd(counts + dst[t], 1);
}

// 49 blocks: block-sum of 1024 counts -> bsum[b]
__global__ __launch_bounds__(256) void gat_scan_partial(
    const int* __restrict__ counts, int* __restrict__ bsum) {
  const int lane = threadIdx.x & 63;
  const int wid = threadIdx.x >> 6;
  int i4 = blockIdx.x * 256 + threadIdx.x;
  int4 c = (i4 < N_I4) ? ((const int4*)counts)[i4] : make_int4(0, 0, 0, 0);
  int s = c.x + c.y + c.z + c.w;
#pragma unroll
  for (int off = 32; off; off >>= 1) s += __shfl_xor(s, off, 64);
  __shared__ int ws[4];
  if (lane == 0) ws[wid] = s;
  __syncthreads();
  if (threadIdx.x == 0) bsum[blockIdx.x] = ws[0] + ws[1] + ws[2] + ws[3];
}

// 1 block x 64: exclusive scan of 49 block sums -> bbase; total -> offsets[N]
__global__ __launch_bounds__(64) void gat_scan_base(
    const int* __restrict__ bsum, int* __restrict__ bbase,
    int* __restrict__ offsets) {
  const int t = threadIdx.x;
  int v = (t < N_SBLK) ? bsum[t] : 0;
  int incl = v;
#pragma unroll
  for (int off = 1; off < 64; off <<= 1) {
    int u = __shfl_up(incl, off, 64);
    if (t >= off) incl += u;
  }
  if (t < N_SBLK) bbase[t] = incl - v;
  if (t == 63) offsets[N_NODES] = incl;  // == N_EDGES
}

// 49 blocks: per-block exclusive scan + base; write offsets & cursor (int4)
__global__ __launch_bounds__(256) void gat_scan_final(
    const int* __restrict__ counts, const int* __restrict__ bbase,
    int* __restrict__ offsets, int* __restrict__ cursor) {
  const int lane = threadIdx.x & 63;
  const int wid = threadIdx.x >> 6;
  int i4 = blockIdx.x * 256 + threadIdx.x;
  int4 c = (i4 < N_I4) ? ((const int4*)counts)[i4] : make_int4(0, 0, 0, 0);
  int s = c.x + c.y + c.z + c.w;
  int incl = s;
#pragma unroll
  for (int off = 1; off < 64; off <<= 1) {
    int u = __shfl_up(incl, off, 64);
    if (lane >= off) incl += u;
  }
  __shared__ int ws[4];
  if (lane == 63) ws[wid] = incl;
  __syncthreads();
  int wb = 0;
#pragma unroll
  for (int k = 0; k < 4; ++k)
    if (k < wid) wb += ws[k];
  int ex = bbase[blockIdx.x] + wb + (incl - s);
  int4 o;
  o.x = ex;
  o.y = o.x + c.x;
  o.z = o.y + c.y;
  o.w = o.z + c.z;
  if (i4 < N_I4) {
    ((int4*)offsets)[i4] = o;
    ((int4*)cursor)[i4] = o;
  }
}

__global__ __launch_bounds__(256) void gat_escatter(
    const int* __restrict__ src, const int* __restrict__ dst,
    int* __restrict__ cursor, int* __restrict__ ssorted) {
  int t = blockIdx.x * blockDim.x + threadIdx.x;
  if (t >= N_EDGES) return;
  int d = dst[t];
  int p = atomicAdd(cursor + d, 1);
  ssorted[p] = src[t];
}

// ---------------------------------------------------------------------------
// Aggregation: one wave per dst node (lane = output column). No atomics.
// ---------------------------------------------------------------------------
__global__ __launch_bounds__(256) void gat_agg(
    const float* __restrict__ z, const float* __restrict__ asrc,
    const float* __restrict__ adst, const int* __restrict__ offsets,
    const int* __restrict__ ssorted, float* __restrict__ out) {
  const int lane = threadIdx.x & 63;
  const int node = (blockIdx.x * blockDim.x + threadIdx.x) >> 6;
  if (node >= N_NODES) return;
  const int o0 = offsets[node];
  const int o1 = offsets[node + 1];
  if (o0 == o1) {
    out[(size_t)node * OUT_DIM + lane] = 0.f;
    return;
  }
  const float ad = adst[node];

  float m = NEG_INF;
  for (int base = o0; base < o1; base += 64) {
    int idx = base + lane;
    float ev = NEG_INF;
    if (idx < o1) {
      float v = asrc[ssorted[idx]] + ad;
      ev = v > 0.f ? v : NEG_SLOPE * v;
    }
#pragma unroll
    for (int off = 32; off; off >>= 1) ev = fmaxf(ev, __shfl_xor(ev, off, 64));
    m = fmaxf(m, ev);
  }

  float acc = 0.f, dsum = 0.f;
  for (int base = o0; base < o1; base += 64) {
    int idx = base + lane;
    int s = 0;
    float w = 0.f;
    if (idx < o1) {
      s = ssorted[idx];
      float v = asrc[s] + ad;
      v = v > 0.f ? v : NEG_SLOPE * v;
      w = __expf(v - m);
    }
    dsum += w;
    const int cnt = min(64, o1 - base);
    for (int j = 0; j < cnt; ++j) {
      float wj = __shfl(w, j, 64);
      int sj = __shfl(s, j, 64);
      acc = fmaf(wj, z[(size_t)sj * OUT_DIM + lane], acc);
    }
  }
#pragma unroll
  for (int off = 32; off; off >>= 1) dsum += __shfl_xor(dsum, off, 64);

  float h = acc / (dsum > 0.f ? dsum : 1.f);
  out[(size_t)node * OUT_DIM + lane] = h > 0.f ? h : expm1f(h);
}

// ---------------------------------------------------------------------------
extern "C" void kernel_launch(void* const* d_in, const int* in_sizes, int n_in,
                              void* d_out, int out_size, void* d_ws, size_t ws_size,
                              hipStream_t stream) {
  const float* feat  = (const float*)d_in[0];
  const float* fcw   = (const float*)d_in[1];
  const float* attnw = (const float*)d_in[2];
  const int* src     = (const int*)d_in[3];
  const int* dst     = (const int*)d_in[4];
  float* out = (float*)d_out;

  char* ws = (char*)d_ws;
  float* z = (float*)ws;      ws += (size_t)N_NODES * OUT_DIM * sizeof(float);  // 12.8 MB
  float* asrc = (float*)ws;   ws += (size_t)N_NODES * sizeof(float);
  float* adst = (float*)ws;   ws += (size_t)N_NODES * sizeof(float);
  int* counts = (int*)ws;     ws += (size_t)N_NODES * sizeof(int);
  int* cursor = (int*)ws;     ws += (size_t)N_NODES * sizeof(int);
  int* offsets = (int*)ws;    ws += (size_t)(N_NODES + 4) * sizeof(int);  // padded to 16B
  int* bsum = (int*)ws;       ws += 64 * sizeof(int);
  int* bbase = (int*)ws;      ws += 64 * sizeof(int);
  int* ssorted = (int*)ws;    ws += (size_t)N_EDGES * sizeof(int);              // 3.2 MB

  hipMemsetAsync(counts, 0, (size_t)N_NODES * sizeof(int), stream);

  gat_z<<<800, 256, 0, stream>>>(feat, fcw, attnw, z, asrc, adst);
  gat_hist<<<(N_EDGES + 255) / 256, 256, 0, stream>>>(dst, counts);
  gat_scan_partial<<<N_SBLK, 256, 0, stream>>>(counts, bsum);
  gat_scan_base<<<1, 64, 0, stream>>>(bsum, bbase, offsets);
  gat_scan_final<<<N_SBLK, 256, 0, stream>>>(counts, bbase, offsets, cursor);
  gat_escatter<<<(N_EDGES + 255) / 256, 256, 0, stream>>>(src, dst, cursor, ssorted);
  gat_agg<<<(N_NODES * 64 + 255) / 256, 256, 0, stream>>>(z, asrc, adst, offsets, ssorted, out);
}

// Round 4
// 230.138 us; speedup vs baseline: 1.7459x; 1.1497x over previous
//
#include <hip/hip_runtime.h>
#include <hip/hip_bf16.h>

#define N_NODES 50000
#define N_EDGES 800000
#define IN_DIM 128
#define OUT_DIM 64
#define NEG_SLOPE 0.01f
#define NEG_INF (-3.0e38f)

#define N_I4 (N_NODES / 4)          // 12500 int4 elements (N_NODES % 4 == 0)
#define N_SBLK ((N_I4 + 255) / 256) // 49 scan blocks (1024 nodes each)
#define Z_BLOCKS 800
#define HIST_BLOCKS ((N_EDGES + 255) / 256)

__device__ __forceinline__ float rlanef(float v, int l) {
  return __uint_as_float(__builtin_amdgcn_readlane(__float_as_uint(v), l));
}
__device__ __forceinline__ int rlanei(int v, int l) {
  return __builtin_amdgcn_readlane(v, l);
}

// ---------------------------------------------------------------------------
// Stage 1 (fused): blocks [0, Z_BLOCKS) compute z = feat @ fcw^T plus
// a_src/a_dst; blocks [Z_BLOCKS, ...) histogram dst into counts.
// ---------------------------------------------------------------------------
__global__ __launch_bounds__(256, 2) void gat_z_hist(
    const float* __restrict__ feat, const float* __restrict__ fcw,
    const float* __restrict__ attnw, float* __restrict__ z,
    float* __restrict__ asrc, float* __restrict__ adst,
    const int* __restrict__ dst, int* __restrict__ counts) {
  if (blockIdx.x >= Z_BLOCKS) {
    int t = (blockIdx.x - Z_BLOCKS) * 256 + threadIdx.x;
    if (t < N_EDGES) atomicAdd(counts + dst[t], 1);
    return;
  }
  __shared__ float rows[4][IN_DIM];
  const int lane = threadIdx.x & 63;
  const int wslot = threadIdx.x >> 6;
  const int wave = (blockIdx.x * blockDim.x + threadIdx.x) >> 6;
  const int nwaves = Z_BLOCKS * 4;

  float w[IN_DIM];
  {
    const float4* wr = (const float4*)(fcw + (size_t)lane * IN_DIM);
#pragma unroll
    for (int i = 0; i < IN_DIM / 4; ++i) ((float4*)w)[i] = wr[i];
  }
  const float aws = attnw[lane];
  const float awd = attnw[OUT_DIM + lane];

  int node = wave;
  float2 cur = make_float2(0.f, 0.f);
  if (node < N_NODES)
    cur = *(const float2*)(feat + (size_t)node * IN_DIM + 2 * lane);

  for (; node < N_NODES; node += nwaves) {
    ((float2*)rows[wslot])[lane] = cur;
    int nxt = node + nwaves;
    float2 nf = make_float2(0.f, 0.f);
    if (nxt < N_NODES)
      nf = *(const float2*)(feat + (size_t)nxt * IN_DIM + 2 * lane);

    float a0 = 0.f, a1 = 0.f, a2 = 0.f, a3 = 0.f;
#pragma unroll
    for (int k = 0; k < IN_DIM; k += 4) {
      const float4 f = *(const float4*)&rows[wslot][k];
      a0 = fmaf(f.x, w[k + 0], a0);
      a1 = fmaf(f.y, w[k + 1], a1);
      a2 = fmaf(f.z, w[k + 2], a2);
      a3 = fmaf(f.w, w[k + 3], a3);
    }
    float acc = (a0 + a1) + (a2 + a3);
    z[(size_t)node * OUT_DIM + lane] = acc;

    float s = acc * aws, d = acc * awd;
#pragma unroll
    for (int off = 32; off; off >>= 1) {
      s += __shfl_xor(s, off, 64);
      d += __shfl_xor(d, off, 64);
    }
    if (lane == 0) {
      asrc[node] = s;
      adst[node] = d;
    }
    cur = nf;
  }
}

// ---------------------------------------------------------------------------
// Hierarchical exclusive scan (3 kernels) + bucket scatter.
// ---------------------------------------------------------------------------
__global__ __launch_bounds__(256) void gat_scan_partial(
    const int* __restrict__ counts, int* __restrict__ bsum) {
  const int lane = threadIdx.x & 63;
  const int wid = threadIdx.x >> 6;
  int i4 = blockIdx.x * 256 + threadIdx.x;
  int4 c = (i4 < N_I4) ? ((const int4*)counts)[i4] : make_int4(0, 0, 0, 0);
  int s = c.x + c.y + c.z + c.w;
#pragma unroll
  for (int off = 32; off; off >>= 1) s += __shfl_xor(s, off, 64);
  __shared__ int ws[4];
  if (lane == 0) ws[wid] = s;
  __syncthreads();
  if (threadIdx.x == 0) bsum[blockIdx.x] = ws[0] + ws[1] + ws[2] + ws[3];
}

__global__ __launch_bounds__(64) void gat_scan_base(
    const int* __restrict__ bsum, int* __restrict__ bbase,
    int* __restrict__ offsets) {
  const int t = threadIdx.x;
  int v = (t < N_SBLK) ? bsum[t] : 0;
  int incl = v;
#pragma unroll
  for (int off = 1; off < 64; off <<= 1) {
    int u = __shfl_up(incl, off, 64);
    if (t >= off) incl += u;
  }
  if (t < N_SBLK) bbase[t] = incl - v;
  if (t == 63) offsets[N_NODES] = incl;  // == N_EDGES
}

__global__ __launch_bounds__(256) void gat_scan_final(
    const int* __restrict__ counts, const int* __restrict__ bbase,
    int* __restrict__ offsets, int* __restrict__ cursor) {
  const int lane = threadIdx.x & 63;
  const int wid = threadIdx.x >> 6;
  int i4 = blockIdx.x * 256 + threadIdx.x;
  int4 c = (i4 < N_I4) ? ((const int4*)counts)[i4] : make_int4(0, 0, 0, 0);
  int s = c.x + c.y + c.z + c.w;
  int incl = s;
#pragma unroll
  for (int off = 1; off < 64; off <<= 1) {
    int u = __shfl_up(incl, off, 64);
    if (lane >= off) incl += u;
  }
  __shared__ int ws[4];
  if (lane == 63) ws[wid] = incl;
  __syncthreads();
  int wb = 0;
#pragma unroll
  for (int k = 0; k < 4; ++k)
    if (k < wid) wb += ws[k];
  int ex = bbase[blockIdx.x] + wb + (incl - s);
  int4 o;
  o.x = ex;
  o.y = o.x + c.x;
  o.z = o.y + c.y;
  o.w = o.z + c.z;
  if (i4 < N_I4) {
    ((int4*)offsets)[i4] = o;
    ((int4*)cursor)[i4] = o;
  }
}

__global__ __launch_bounds__(256) void gat_escatter(
    const int* __restrict__ src, const int* __restrict__ dst,
    int* __restrict__ cursor, int* __restrict__ ssorted) {
  int t = blockIdx.x * blockDim.x + threadIdx.x;
  if (t >= N_EDGES) return;
  int d = dst[t];
  int p = atomicAdd(cursor + d, 1);
  ssorted[p] = src[t];
}

// ---------------------------------------------------------------------------
// Aggregation: one wave per dst node, online softmax, readlane broadcasts,
// 4-wide unrolled gather-accumulate (4 z-row loads in flight). No atomics.
// ---------------------------------------------------------------------------
__global__ __launch_bounds__(256) void gat_agg(
    const float* __restrict__ z, const float* __restrict__ asrc,
    const float* __restrict__ adst, const int* __restrict__ offsets,
    const int* __restrict__ ssorted, float* __restrict__ out) {
  const int lane = threadIdx.x & 63;
  const int node = (blockIdx.x * blockDim.x + threadIdx.x) >> 6;
  if (node >= N_NODES) return;
  const int o0 = offsets[node];
  const int o1 = offsets[node + 1];
  if (o0 == o1) {  // no incoming edges: elu(0/1) = 0
    out[(size_t)node * OUT_DIM + lane] = 0.f;
    return;
  }
  const float ad = adst[node];

  float m = NEG_INF, dsum = 0.f;
  float acc0 = 0.f, acc1 = 0.f, acc2 = 0.f, acc3 = 0.f;

  for (int base = o0; base < o1; base += 64) {
    const int cnt = min(64, o1 - base);
    int s = 0;
    float ev = NEG_INF;
    if (lane < cnt) {
      s = ssorted[base + lane];
      float v = asrc[s] + ad;
      ev = v > 0.f ? v : NEG_SLOPE * v;
    }
    // chunk max
    float cm = ev;
#pragma unroll
    for (int off = 32; off; off >>= 1) cm = fmaxf(cm, __shfl_xor(cm, off, 64));
    const float nm = fmaxf(m, cm);
    const float scale = __expf(m - nm);  // first chunk: exp(-inf) = 0
    dsum *= scale;
    acc0 *= scale; acc1 *= scale; acc2 *= scale; acc3 *= scale;
    m = nm;

    float w = (lane < cnt) ? __expf(ev - m) : 0.f;
    dsum += w;

    int j = 0;
    for (; j + 4 <= cnt; j += 4) {
      const int s0 = rlanei(s, j + 0), s1 = rlanei(s, j + 1);
      const int s2 = rlanei(s, j + 2), s3 = rlanei(s, j + 3);
      const float w0 = rlanef(w, j + 0), w1 = rlanef(w, j + 1);
      const float w2 = rlanef(w, j + 2), w3 = rlanef(w, j + 3);
      const float z0 = z[(size_t)s0 * OUT_DIM + lane];
      const float z1 = z[(size_t)s1 * OUT_DIM + lane];
      const float z2 = z[(size_t)s2 * OUT_DIM + lane];
      const float z3 = z[(size_t)s3 * OUT_DIM + lane];
      acc0 = fmaf(w0, z0, acc0);
      acc1 = fmaf(w1, z1, acc1);
      acc2 = fmaf(w2, z2, acc2);
      acc3 = fmaf(w3, z3, acc3);
    }
    for (; j < cnt; ++j) {
      const int sj = rlanei(s, j);
      const float wj = rlanef(w, j);
      acc0 = fmaf(wj, z[(size_t)sj * OUT_DIM + lane], acc0);
    }
  }
  float acc = (acc0 + acc1) + (acc2 + acc3);
#pragma unroll
  for (int off = 32; off; off >>= 1) dsum += __shfl_xor(dsum, off, 64);

  const float h = acc / (dsum > 0.f ? dsum : 1.f);
  out[(size_t)node * OUT_DIM + lane] = h > 0.f ? h : expm1f(h);
}

// ---------------------------------------------------------------------------
extern "C" void kernel_launch(void* const* d_in, const int* in_sizes, int n_in,
                              void* d_out, int out_size, void* d_ws, size_t ws_size,
                              hipStream_t stream) {
  const float* feat  = (const float*)d_in[0];
  const float* fcw   = (const float*)d_in[1];
  const float* attnw = (const float*)d_in[2];
  const int* src     = (const int*)d_in[3];
  const int* dst     = (const int*)d_in[4];
  float* out = (float*)d_out;

  char* ws = (char*)d_ws;
  float* z = (float*)ws;      ws += (size_t)N_NODES * OUT_DIM * sizeof(float);  // 12.8 MB
  float* asrc = (float*)ws;   ws += (size_t)N_NODES * sizeof(float);
  float* adst = (float*)ws;   ws += (size_t)N_NODES * sizeof(float);
  int* counts = (int*)ws;     ws += (size_t)N_NODES * sizeof(int);
  int* cursor = (int*)ws;     ws += (size_t)N_NODES * sizeof(int);
  int* offsets = (int*)ws;    ws += (size_t)(N_NODES + 4) * sizeof(int);  // padded to 16B
  int* bsum = (int*)ws;       ws += 64 * sizeof(int);
  int* bbase = (int*)ws;      ws += 64 * sizeof(int);
  int* ssorted = (int*)ws;    ws += (size_t)N_EDGES * sizeof(int);              // 3.2 MB

  hipMemsetAsync(counts, 0, (size_t)N_NODES * sizeof(int), stream);

  gat_z_hist<<<Z_BLOCKS + HIST_BLOCKS, 256, 0, stream>>>(feat, fcw, attnw, z,
                                                         asrc, adst, dst, counts);
  gat_scan_partial<<<N_SBLK, 256, 0, stream>>>(counts, bsum);
  gat_scan_base<<<1, 64, 0, stream>>>(bsum, bbase, offsets);
  gat_scan_final<<<N_SBLK, 256, 0, stream>>>(counts, bbase, offsets, cursor);
  gat_escatter<<<(N_EDGES + 255) / 256, 256, 0, stream>>>(src, dst, cursor, ssorted);
  gat_agg<<<(N_NODES * 64 + 255) / 256, 256, 0, stream>>>(z, asrc, adst, offsets, ssorted, out);
}

// Round 5
// 216.770 us; speedup vs baseline: 1.8535x; 1.0617x over previous
//
#include <hip/hip_runtime.h>
#include <hip/hip_bf16.h>

#define N_NODES 50000
#define N_EDGES 800000
#define IN_DIM 128
#define OUT_DIM 64
#define NEG_SLOPE 0.01f
#define NEG_INF (-3.0e38f)

#define N_I4 (N_NODES / 4)          // 12500 int4 elements
#define N_SBLK ((N_I4 + 255) / 256) // 49 scan blocks
#define NT 16                        // nodes per z-tile
#define N_TILES (N_NODES / NT)       // 3125
#define Z_BLOCKS 1024
#define E_I4 (N_EDGES / 4)           // 200000
#define HIST_BLOCKS ((E_I4 + 255) / 256)

__device__ __forceinline__ float rlanef(float v, int l) {
  return __uint_as_float(__builtin_amdgcn_readlane(__float_as_uint(v), l));
}
__device__ __forceinline__ int rlanei(int v, int l) {
  return __builtin_amdgcn_readlane(v, l);
}

// ---------------------------------------------------------------------------
// Stage 1 (fused): blocks [0, Z_BLOCKS): tiled z-GEMM. Wave q owns K-quarter
// [32q,32q+32); lane j holds 32 weight VGPRs (no spill). 16-node tiles staged
// in LDS; partials reduced across waves in LDS; fused a_src/a_dst.
// Blocks [Z_BLOCKS, ...): dst histogram (int4-vectorized).
// ---------------------------------------------------------------------------
__global__ __launch_bounds__(256) void gat_z_hist(
    const float* __restrict__ feat, const float* __restrict__ fcw,
    const float* __restrict__ attnw, float* __restrict__ z,
    float* __restrict__ asrc, float* __restrict__ adst,
    const int* __restrict__ dst, int* __restrict__ counts) {
  if (blockIdx.x >= Z_BLOCKS) {
    int t = (blockIdx.x - Z_BLOCKS) * 256 + threadIdx.x;
    if (t < E_I4) {
      int4 d = ((const int4*)dst)[t];
      atomicAdd(counts + d.x, 1);
      atomicAdd(counts + d.y, 1);
      atomicAdd(counts + d.z, 1);
      atomicAdd(counts + d.w, 1);
    }
    return;
  }

  __shared__ float flds[NT][IN_DIM];      // 8 KB feature tile
  __shared__ float part[4][NT][OUT_DIM];  // 16 KB partial sums

  const int tid = threadIdx.x;
  const int lane = tid & 63;
  const int q = tid >> 6;  // wave id == K-quarter

  // lane j of wave q: fcw[j][32q .. 32q+32) -> 32 VGPRs (elementwise to SROA)
  float wq[32];
  {
    const float4* wr = (const float4*)(fcw + (size_t)lane * IN_DIM + q * 32);
#pragma unroll
    for (int i = 0; i < 8; ++i) {
      float4 t4 = wr[i];
      wq[4 * i + 0] = t4.x;
      wq[4 * i + 1] = t4.y;
      wq[4 * i + 2] = t4.z;
      wq[4 * i + 3] = t4.w;
    }
  }
  const float aws = attnw[lane];
  const float awd = attnw[OUT_DIM + lane];

  for (int tile = blockIdx.x; tile < N_TILES; tile += Z_BLOCKS) {
    const int n0 = tile * NT;
    // stage 16 x 128 floats, coalesced float4 x2 per thread
    {
      const float4* gsrc = (const float4*)(feat + (size_t)n0 * IN_DIM);
      float4* ldst = (float4*)flds;
      ldst[tid] = gsrc[tid];
      ldst[tid + 256] = gsrc[tid + 256];
    }
    __syncthreads();

    // compute: 16 nodes x 32 FMAs (LDS reads are wave-uniform broadcasts)
#pragma unroll
    for (int n = 0; n < NT; ++n) {
      const float* fr = &flds[n][q * 32];
      float a0 = 0.f, a1 = 0.f, a2 = 0.f, a3 = 0.f;
#pragma unroll
      for (int k = 0; k < 32; k += 4) {
        a0 = fmaf(fr[k + 0], wq[k + 0], a0);
        a1 = fmaf(fr[k + 1], wq[k + 1], a1);
        a2 = fmaf(fr[k + 2], wq[k + 2], a2);
        a3 = fmaf(fr[k + 3], wq[k + 3], a3);
      }
      part[q][n][lane] = (a0 + a1) + (a2 + a3);
    }
    __syncthreads();

    // reduce: wave q finalizes nodes 4q..4q+3; fused a_src/a_dst
#pragma unroll
    for (int r = 0; r < 4; ++r) {
      const int n = q * 4 + r;
      float zv = part[0][n][lane] + part[1][n][lane] + part[2][n][lane] +
                 part[3][n][lane];
      z[(size_t)(n0 + n) * OUT_DIM + lane] = zv;
      float s = zv * aws, d = zv * awd;
#pragma unroll
      for (int off = 32; off; off >>= 1) {
        s += __shfl_xor(s, off, 64);
        d += __shfl_xor(d, off, 64);
      }
      if (lane == 0) {
        asrc[n0 + n] = s;
        adst[n0 + n] = d;
      }
    }
    __syncthreads();  // part/flds reused next tile
  }
}

// ---------------------------------------------------------------------------
// Hierarchical exclusive scan (3 kernels) + bucket scatter.
// ---------------------------------------------------------------------------
__global__ __launch_bounds__(256) void gat_scan_partial(
    const int* __restrict__ counts, int* __restrict__ bsum) {
  const int lane = threadIdx.x & 63;
  const int wid = threadIdx.x >> 6;
  int i4 = blockIdx.x * 256 + threadIdx.x;
  int4 c = (i4 < N_I4) ? ((const int4*)counts)[i4] : make_int4(0, 0, 0, 0);
  int s = c.x + c.y + c.z + c.w;
#pragma unroll
  for (int off = 32; off; off >>= 1) s += __shfl_xor(s, off, 64);
  __shared__ int ws[4];
  if (lane == 0) ws[wid] = s;
  __syncthreads();
  if (threadIdx.x == 0) bsum[blockIdx.x] = ws[0] + ws[1] + ws[2] + ws[3];
}

__global__ __launch_bounds__(64) void gat_scan_base(
    const int* __restrict__ bsum, int* __restrict__ bbase,
    int* __restrict__ offsets) {
  const int t = threadIdx.x;
  int v = (t < N_SBLK) ? bsum[t] : 0;
  int incl = v;
#pragma unroll
  for (int off = 1; off < 64; off <<= 1) {
    int u = __shfl_up(incl, off, 64);
    if (t >= off) incl += u;
  }
  if (t < N_SBLK) bbase[t] = incl - v;
  if (t == 63) offsets[N_NODES] = incl;  // == N_EDGES
}

__global__ __launch_bounds__(256) void gat_scan_final(
    const int* __restrict__ counts, const int* __restrict__ bbase,
    int* __restrict__ offsets, int* __restrict__ cursor) {
  const int lane = threadIdx.x & 63;
  const int wid = threadIdx.x >> 6;
  int i4 = blockIdx.x * 256 + threadIdx.x;
  int4 c = (i4 < N_I4) ? ((const int4*)counts)[i4] : make_int4(0, 0, 0, 0);
  int s = c.x + c.y + c.z + c.w;
  int incl = s;
#pragma unroll
  for (int off = 1; off < 64; off <<= 1) {
    int u = __shfl_up(incl, off, 64);
    if (lane >= off) incl += u;
  }
  __shared__ int ws[4];
  if (lane == 63) ws[wid] = incl;
  __syncthreads();
  int wb = 0;
#pragma unroll
  for (int k = 0; k < 4; ++k)
    if (k < wid) wb += ws[k];
  int ex = bbase[blockIdx.x] + wb + (incl - s);
  int4 o;
  o.x = ex;
  o.y = o.x + c.x;
  o.z = o.y + c.y;
  o.w = o.z + c.z;
  if (i4 < N_I4) {
    ((int4*)offsets)[i4] = o;
    ((int4*)cursor)[i4] = o;
  }
}

// int4-vectorized bucket scatter: 4 independent atomic+store chains/thread
__global__ __launch_bounds__(256) void gat_escatter(
    const int* __restrict__ src, const int* __restrict__ dst,
    int* __restrict__ cursor, int* __restrict__ ssorted) {
  int t = blockIdx.x * blockDim.x + threadIdx.x;
  if (t >= E_I4) return;
  int4 s = ((const int4*)src)[t];
  int4 d = ((const int4*)dst)[t];
  int p0 = atomicAdd(cursor + d.x, 1);
  int p1 = atomicAdd(cursor + d.y, 1);
  int p2 = atomicAdd(cursor + d.z, 1);
  int p3 = atomicAdd(cursor + d.w, 1);
  ssorted[p0] = s.x;
  ssorted[p1] = s.y;
  ssorted[p2] = s.z;
  ssorted[p3] = s.w;
}

// ---------------------------------------------------------------------------
// Aggregation: one wave per dst node, online softmax, readlane broadcasts,
// 4-wide unrolled gather-accumulate. No atomics.
// ---------------------------------------------------------------------------
__global__ __launch_bounds__(256) void gat_agg(
    const float* __restrict__ z, const float* __restrict__ asrc,
    const float* __restrict__ adst, const int* __restrict__ offsets,
    const int* __restrict__ ssorted, float* __restrict__ out) {
  const int lane = threadIdx.x & 63;
  const int node = (blockIdx.x * blockDim.x + threadIdx.x) >> 6;
  if (node >= N_NODES) return;
  const int o0 = offsets[node];
  const int o1 = offsets[node + 1];
  if (o0 == o1) {
    out[(size_t)node * OUT_DIM + lane] = 0.f;
    return;
  }
  const float ad = adst[node];

  float m = NEG_INF, dsum = 0.f;
  float acc0 = 0.f, acc1 = 0.f, acc2 = 0.f, acc3 = 0.f;

  for (int base = o0; base < o1; base += 64) {
    const int cnt = min(64, o1 - base);
    int s = 0;
    float ev = NEG_INF;
    if (lane < cnt) {
      s = ssorted[base + lane];
      float v = asrc[s] + ad;
      ev = v > 0.f ? v : NEG_SLOPE * v;
    }
    float cm = ev;
#pragma unroll
    for (int off = 32; off; off >>= 1) cm = fmaxf(cm, __shfl_xor(cm, off, 64));
    const float nm = fmaxf(m, cm);
    const float scale = __expf(m - nm);  // first chunk: exp(-inf) = 0
    dsum *= scale;
    acc0 *= scale; acc1 *= scale; acc2 *= scale; acc3 *= scale;
    m = nm;

    float w = (lane < cnt) ? __expf(ev - m) : 0.f;
    dsum += w;

    int j = 0;
    for (; j + 4 <= cnt; j += 4) {
      const int s0 = rlanei(s, j + 0), s1 = rlanei(s, j + 1);
      const int s2 = rlanei(s, j + 2), s3 = rlanei(s, j + 3);
      const float w0 = rlanef(w, j + 0), w1 = rlanef(w, j + 1);
      const float w2 = rlanef(w, j + 2), w3 = rlanef(w, j + 3);
      const float z0 = z[(size_t)s0 * OUT_DIM + lane];
      const float z1 = z[(size_t)s1 * OUT_DIM + lane];
      const float z2 = z[(size_t)s2 * OUT_DIM + lane];
      const float z3 = z[(size_t)s3 * OUT_DIM + lane];
      acc0 = fmaf(w0, z0, acc0);
      acc1 = fmaf(w1, z1, acc1);
      acc2 = fmaf(w2, z2, acc2);
      acc3 = fmaf(w3, z3, acc3);
    }
    for (; j < cnt; ++j) {
      const int sj = rlanei(s, j);
      const float wj = rlanef(w, j);
      acc0 = fmaf(wj, z[(size_t)sj * OUT_DIM + lane], acc0);
    }
  }
  float acc = (acc0 + acc1) + (acc2 + acc3);
#pragma unroll
  for (int off = 32; off; off >>= 1) dsum += __shfl_xor(dsum, off, 64);

  const float h = acc / (dsum > 0.f ? dsum : 1.f);
  out[(size_t)node * OUT_DIM + lane] = h > 0.f ? h : expm1f(h);
}

// ---------------------------------------------------------------------------
extern "C" void kernel_launch(void* const* d_in, const int* in_sizes, int n_in,
                              void* d_out, int out_size, void* d_ws, size_t ws_size,
                              hipStream_t stream) {
  const float* feat  = (const float*)d_in[0];
  const float* fcw   = (const float*)d_in[1];
  const float* attnw = (const float*)d_in[2];
  const int* src     = (const int*)d_in[3];
  const int* dst     = (const int*)d_in[4];
  float* out = (float*)d_out;

  char* ws = (char*)d_ws;
  float* z = (float*)ws;      ws += (size_t)N_NODES * OUT_DIM * sizeof(float);  // 12.8 MB
  float* asrc = (float*)ws;   ws += (size_t)N_NODES * sizeof(float);
  float* adst = (float*)ws;   ws += (size_t)N_NODES * sizeof(float);
  int* counts = (int*)ws;     ws += (size_t)N_NODES * sizeof(int);
  int* cursor = (int*)ws;     ws += (size_t)N_NODES * sizeof(int);
  int* offsets = (int*)ws;    ws += (size_t)(N_NODES + 4) * sizeof(int);  // padded
  int* bsum = (int*)ws;       ws += 64 * sizeof(int);
  int* bbase = (int*)ws;      ws += 64 * sizeof(int);
  int* ssorted = (int*)ws;    ws += (size_t)N_EDGES * sizeof(int);              // 3.2 MB

  hipMemsetAsync(counts, 0, (size_t)N_NODES * sizeof(int), stream);

  gat_z_hist<<<Z_BLOCKS + HIST_BLOCKS, 256, 0, stream>>>(feat, fcw, attnw, z,
                                                         asrc, adst, dst, counts);
  gat_scan_partial<<<N_SBLK, 256, 0, stream>>>(counts, bsum);
  gat_scan_base<<<1, 64, 0, stream>>>(bsum, bbase, offsets);
  gat_scan_final<<<N_SBLK, 256, 0, stream>>>(counts, bbase, offsets, cursor);
  gat_escatter<<<HIST_BLOCKS, 256, 0, stream>>>(src, dst, cursor, ssorted);
  gat_agg<<<(N_NODES * 64 + 255) / 256, 256, 0, stream>>>(z, asrc, adst, offsets, ssorted, out);
}